// Round 14
// baseline (264.115 us; speedup 1.0000x reference)
//
#include <hip/hip_runtime.h>
#include <math.h>
#include <float.h>

// Problem constants (B=16, T=4096, D=64, K=1024)
#define NROWS    65536
#define DD       64
#define KK       1024
#define LOSS_OFF 4194304
#define IDX_OFF  4194305
#define RPB      128          // rows per block (8 waves x 16 rows)  [r7-verified]
#define MAXC     16           // candidate capacity (overflow -> full-K fallback)
#define TPR      16           // tiles per round (16 codes each, 2/wave)
#define NRND     4            // rounds (single pass)
#define NBLK     (NROWS / RPB)   // 512 blocks
#define WS_NEED  (4096 + 131072 + 4096)   // bn + ebf + psum

typedef short  short8 __attribute__((ext_vector_type(8)));   // 8 bf16
typedef float  f32x4  __attribute__((ext_vector_type(4)));

// Async global->LDS, 16B/lane (r10-verified; m97/m104 semantics).
__device__ __forceinline__ void async_copy16(void* lds, const void* g) {
    __builtin_amdgcn_global_load_lds(
        (const __attribute__((address_space(1))) unsigned int*)g,
        (__attribute__((address_space(3))) unsigned int*)lds, 16, 0, 0);
}

// float -> bf16 bits, RNE. Filter-side only.
__device__ __forceinline__ unsigned short bf16rne(float x) {
    unsigned int u = __float_as_uint(x);
    return (unsigned short)((u + 0x7fffu + ((u >> 16) & 1u)) >> 16);
}

// numpy strided accumulator r_j for n=64 pairwise sum (r6/r7-verified).
__device__ __forceinline__ float np_acc8(const float* p, int j) {
#pragma clang fp contract(off)
    float r = 0.f;
#pragma unroll
    for (int i = 0; i < 8; ++i) {
        const float v = p[8 * i + j];
        r += v * v;
    }
    return r;
}

// Prep (r5 layout, verified): norms bit-exact + fragment-ordered ebf:
// tile g stored as [1024B b0 frags in lane order][1024B b1 frags].
// SEPARATE DISPATCH is load-bearing: the kernel boundary flushes/invalidates
// caches so all XCDs read fresh ebf/bn (r13 cooperative fusion produced
// stale-L2 garbage indices — do not re-fuse without cache-control asm).
__global__ void vq_prep(const float* __restrict__ emb,
                        float* __restrict__ bn,
                        unsigned short* __restrict__ ebf) {
#pragma clang fp contract(off)
    const int gtid = blockIdx.x * 256 + threadIdx.x;   // 8192 threads
    const int code = gtid >> 3;
    const int j    = gtid & 7;
    const float* ep = emb + (size_t)code * DD;
    float r = 0.f;
#pragma unroll
    for (int i = 0; i < 8; ++i) {
        const float v = ep[8 * i + j];
        r += v * v;
    }
    const float s1 = r  + __shfl_xor(r,  1, 64);
    const float s2 = s1 + __shfl_xor(s1, 2, 64);
    const float s3 = s2 + __shfl_xor(s2, 4, 64);
    if (j == 0) bn[code] = s3;

    const float* cp = emb + (size_t)gtid * 8;
    const float4 u0 = *reinterpret_cast<const float4*>(cp);
    const float4 u1 = *reinterpret_cast<const float4*>(cp + 4);
    short8 s;
    s[0] = (short)bf16rne(u0.x); s[1] = (short)bf16rne(u0.y);
    s[2] = (short)bf16rne(u0.z); s[3] = (short)bf16rne(u0.w);
    s[4] = (short)bf16rne(u1.x); s[5] = (short)bf16rne(u1.y);
    s[6] = (short)bf16rne(u1.z); s[7] = (short)bf16rne(u1.w);
    const int g    = code >> 4;
    const int c16s = code & 15;
    const int half = j >> 2;
    const int qq   = j & 3;
    const size_t doff = (size_t)g * 1024 + half * 512 + (qq * 16 + c16s) * 8;
    *reinterpret_cast<short8*>(ebf + doff) = s;
}

// Main — r11's verified structure (51.5-53.3us, absmax 0.0) with rounds
// halved again: TPR=16 (2 tiles/wave/round), NRND=4. Same blocks, waves,
// per-wave totals; only the barrier-round count changes (the one lever
// that has ever moved the floor: r3->r7 16->8 rounds = -9.5us). LDS 77.6KB
// -> still 2 blocks/CU. MAXC 32->16 to fit (overflow rows take the
// verified full-K fallback — correctness unchanged).
__global__ __launch_bounds__(512, 4)
void vq_main(const float* __restrict__ z, const float* __restrict__ emb,
             const unsigned short* __restrict__ ebf,
             const float* __restrict__ bn, float* __restrict__ out,
             double* __restrict__ psum) {
    __shared__ char  dbuf[2][TPR * 2048] __attribute__((aligned(16)));  // 64 KB
    __shared__ float a_s[RPB];
    __shared__ float bn_s[KK];
    __shared__ int   cnt[RPB];
    __shared__ int   clist[RPB][MAXC];
    __shared__ int   bidx[RPB];
    __shared__ double lsum[8];

    const int tid  = threadIdx.x;
    const int lane = tid & 63;
    const int wv   = __builtin_amdgcn_readfirstlane(tid) >> 6;   // 0..7
    const int q    = lane >> 4;        // 0..3
    const int c16  = lane & 15;
    const int rowbase = blockIdx.x * RPB;

    // staging source: tile g at ebf + g*2048 bytes, lane reads its own 16B
    // at +lane*16 (b0 KB) and +1024+lane*16 (b1 KB) — contiguous, coalesced.
    const char* sbase = (const char*)ebf + (size_t)lane * 16;
    char* dst0 = &dbuf[0][(2 * wv) * 2048 + lane * 16];
    char* dst1 = &dbuf[1][(2 * wv) * 2048 + lane * 16];

    // ---- phase A: exact row norms, 8 lanes/row, all waves, 2 sweeps ----
    {
        const int j8 = tid & 7;
#pragma unroll
        for (int sw = 0; sw < 2; ++sw) {
            const int rowl = 64 * sw + (tid >> 3);   // 0..127
            const float r = np_acc8(z + (size_t)(rowbase + rowl) * DD, j8);
            const float s1 = r  + __shfl_xor(r,  1, 64);
            const float s2 = s1 + __shfl_xor(s1, 2, 64);
            const float s3 = s2 + __shfl_xor(s2, 4, 64);
            if (j8 == 0) a_s[rowl] = s3;
        }
    }
    if (tid < RPB) cnt[tid] = 0;
    {
        const int i = tid * 2;
        *reinterpret_cast<float2*>(&bn_s[i]) =
            *reinterpret_cast<const float2*>(bn + i);
    }

    // ---- A-fragments (verified layout): rows 16wv+c16, k=32kh+8q+j ----
    short8 afr[2];
#pragma unroll
    for (int kh = 0; kh < 2; ++kh) {
        const float* zp = z + (size_t)(rowbase + 16 * wv + c16) * DD
                          + 32 * kh + 8 * q;
        const float4 u0 = *reinterpret_cast<const float4*>(zp);
        const float4 u1 = *reinterpret_cast<const float4*>(zp + 4);
        short8 s;
        s[0] = (short)bf16rne(u0.x); s[1] = (short)bf16rne(u0.y);
        s[2] = (short)bf16rne(u0.z); s[3] = (short)bf16rne(u0.w);
        s[4] = (short)bf16rne(u1.x); s[5] = (short)bf16rne(u1.y);
        s[6] = (short)bf16rne(u1.z); s[7] = (short)bf16rne(u1.w);
        afr[kh] = s;
    }

    // wave stages tiles (TPR*R + 2wv, +1) each round: 4 coalesced copies
    auto stage = [&](int R, int buf) {
        const char* s0 = sbase + (size_t)(TPR * R + 2 * wv) * 2048;
        char* d = buf ? dst1 : dst0;
        async_copy16(d,        s0);
        async_copy16(d + 1024, s0 + 1024);
        async_copy16(d + 2048, s0 + 2048);
        async_copy16(d + 3072, s0 + 3072);
    };

    stage(0, 0);          // prologue (barrier also publishes phase-A LDS)
    __syncthreads();

    // W = 1.8e-4*||z|| + 1.2e-4 (verified window), per acc reg
    float wadd[4];
#pragma unroll
    for (int i = 0; i < 4; ++i) {
        const int rowl = 16 * wv + 4 * q + i;
        wadd[i] = 1.8e-4f * sqrtf(a_s[rowl]) + 1.2e-4f;
    }

    float mn[4];
#pragma unroll
    for (int i = 0; i < 4; ++i) mn[i] = FLT_MAX;

    // ============ single pass: 4 rounds x 16 tiles, rolling threshold ============
    for (int R = 0; R < NRND; ++R) {
        const int cur = R & 1;
        if (R < NRND - 1) stage(R + 1, cur ^ 1);
        float dv[TPR][4];
#pragma unroll
        for (int j = 0; j < TPR; ++j) {
            const char* tb = &dbuf[cur][j * 2048 + lane * 16];
            const short8 b0 = *reinterpret_cast<const short8*>(tb);
            const short8 b1 = *reinterpret_cast<const short8*>(tb + 1024);
            f32x4 acc = {0.f, 0.f, 0.f, 0.f};
            acc = __builtin_amdgcn_mfma_f32_16x16x32_bf16(afr[0], b0, acc, 0, 0, 0);
            acc = __builtin_amdgcn_mfma_f32_16x16x32_bf16(afr[1], b1, acc, 0, 0, 0);
            const float bnv = bn_s[16 * (TPR * R + j) + c16];
#pragma unroll
            for (int r = 0; r < 4; ++r)
                dv[j][r] = fmaf(-2.f, acc[r], bnv);
        }
        // rolling per-lane min, then cross-lane min over the 16 column-lanes
#pragma unroll
        for (int j = 0; j < TPR; ++j)
#pragma unroll
            for (int r = 0; r < 4; ++r)
                mn[r] = fminf(mn[r], dv[j][r]);
#pragma unroll
        for (int mask = 1; mask < 16; mask <<= 1)
#pragma unroll
            for (int r = 0; r < 4; ++r)
                mn[r] = fminf(mn[r], __shfl_xor(mn[r], mask, 64));
        float thr[4];
#pragma unroll
        for (int r = 0; r < 4; ++r) thr[r] = mn[r] + wadd[r];
        // collect (thr includes this round -> superset of final-min set)
#pragma unroll
        for (int j = 0; j < TPR; ++j) {
            const int col = 16 * (TPR * R + j) + c16;
#pragma unroll
            for (int r = 0; r < 4; ++r) {
                if (dv[j][r] <= thr[r]) {
                    const int rowl = 16 * wv + 4 * q + r;
                    const int slot = atomicAdd(&cnt[rowl], 1);
                    if (slot < MAXC) clist[rowl][slot] = col;
                }
            }
        }
        __syncthreads();   // publish next buffer (vmcnt drained), free cur
    }

    // ---- rescore (verified): exact np chain, lexic (s,k) min ----
    {
        const int rowl = 16 * wv + c16;
        const int row  = rowbase + rowl;
        const int nc   = cnt[rowl];     // rows are wave-private
        const bool full = nc > MAXC;    // overflow insurance
        const int lim  = full ? KK : nc;
        const float av = a_s[rowl];
        const float* zp = z + (size_t)row * DD;
        float sb = FLT_MAX;
        int   cb = 0x7fffffff;
        for (int jj = q; jj < lim; jj += 4) {
            const int c = full ? jj : clist[rowl][jj];
            const float* ep = emb + (size_t)c * DD;
            float dot = 0.f;
#pragma unroll
            for (int d = 0; d < DD; d += 4) {
                const float4 zv = *reinterpret_cast<const float4*>(zp + d);
                const float4 ev = *reinterpret_cast<const float4*>(ep + d);
                dot = fmaf(zv.x, ev.x, dot); dot = fmaf(zv.y, ev.y, dot);
                dot = fmaf(zv.z, ev.z, dot); dot = fmaf(zv.w, ev.w, dot);
            }
            const float tt = av + bn_s[c];
            const float sd = fmaf(-2.f, dot, tt);
            if (sd < sb || (sd == sb && c < cb)) { sb = sd; cb = c; }
        }
#pragma unroll
        for (int mask = 16; mask < 64; mask <<= 1) {
            const float so = __shfl_xor(sb, mask, 64);
            const int   co = __shfl_xor(cb, mask, 64);
            if (so < sb || (so == sb && co < cb)) { sb = so; cb = co; }
        }
        if (cb > 1023) cb = 0;   // safety: never OOB even if logic broke
        if (q == 0) bidx[rowl] = cb;
    }
    __syncthreads();

    // ---- epilogue: 4 threads/row (64B each), all waves, coalesced ----
    {
        const int rowl = tid >> 2;        // 0..127
        const int sub  = tid & 3;         // 0..3, owns floats sub*16..+15
        const int row  = rowbase + rowl;
        const int bid  = bidx[rowl];
        const float* ep = emb + (size_t)bid * DD + sub * 16;
        const float* zp = z + (size_t)row * DD + sub * 16;
        float* op = out + (size_t)row * DD + sub * 16;
        double sac = 0.0;
#pragma unroll
        for (int d = 0; d < 16; d += 4) {
            const float4 zv = *reinterpret_cast<const float4*>(zp + d);
            const float4 e4 = *reinterpret_cast<const float4*>(ep + d);
            const float df0 = e4.x - zv.x;
            const float df1 = e4.y - zv.y;
            const float df2 = e4.z - zv.z;
            const float df3 = e4.w - zv.w;
            float4 qv;
            qv.x = zv.x + df0; qv.y = zv.y + df1;
            qv.z = zv.z + df2; qv.w = zv.w + df3;
            *reinterpret_cast<float4*>(op + d) = qv;
            sac += (double)(df0 * df0); sac += (double)(df1 * df1);
            sac += (double)(df2 * df2); sac += (double)(df3 * df3);
        }
        if (sub == 0) out[IDX_OFF + row] = (float)bid;

        // combine 4 partials per row, then wave sum, then block partial.
        sac += __shfl_down(sac, 1, 64);
        sac += __shfl_down(sac, 2, 64);
        double v = (sub == 0) ? sac : 0.0;
#pragma unroll
        for (int off = 32; off > 0; off >>= 1) v += __shfl_down(v, off, 64);
        if (lane == 0) lsum[wv] = v;
    }
    __syncthreads();
    if (tid == 0) {
        double t = 0.0;
#pragma unroll
        for (int i = 0; i < 8; ++i) t += lsum[i];
        if (psum != nullptr)
            psum[blockIdx.x] = t;   // contention-free partial (vq_fin reduces)
        else
            atomicAdd(&out[LOSS_OFF], (float)((1.25 * t) / 262144.0));
    }
}

// Final reduce: one wave sums the 512 block partials and applies the loss once.
__global__ void vq_fin(const double* __restrict__ psum,
                       float* __restrict__ out) {
    const int lane = threadIdx.x;      // 64 threads
    double t = 0.0;
#pragma unroll
    for (int i = 0; i < 8; ++i) t += psum[lane * 8 + i];
#pragma unroll
    for (int off = 32; off > 0; off >>= 1) t += __shfl_down(t, off, 64);
    if (lane == 0)
        atomicAdd(&out[LOSS_OFF], (float)((1.25 * t) / 262144.0));
}

extern "C" void kernel_launch(void* const* d_in, const int* in_sizes, int n_in,
                              void* d_out, int out_size, void* d_ws, size_t ws_size,
                              hipStream_t stream) {
    const float* z   = (const float*)d_in[0];   // [16,4096,64] fp32
    const float* emb = (const float*)d_in[1];   // [1024,64] fp32
    float* out = (float*)d_out;                 // zq | loss | idx (flat fp32)

    float*          bnw  = (float*)d_ws;                            // 4 KB
    unsigned short* ebf  = (unsigned short*)((char*)d_ws + 4096);   // 128 KB
    // psum only if the workspace provably fits it (r9/r10 failure audit).
    double* psum = (ws_size >= (size_t)WS_NEED)
                   ? (double*)((char*)d_ws + 4096 + 131072) : nullptr;

    vq_prep<<<dim3(32), dim3(256), 0, stream>>>(emb, bnw, ebf);
    vq_main<<<dim3(NBLK), dim3(512), 0, stream>>>(z, emb, ebf, bnw, out, psum);
    if (psum != nullptr)
        vq_fin<<<dim3(1), dim3(64), 0, stream>>>(psum, out);
}

// Round 15
// 228.885 us; speedup vs baseline: 1.1539x; 1.1539x over previous
//
#include <hip/hip_runtime.h>
#include <math.h>
#include <float.h>

// Problem constants (B=16, T=4096, D=64, K=1024)
#define NROWS    65536
#define DD       64
#define KK       1024
#define LOSS_OFF 4194304
#define IDX_OFF  4194305
#define RPB      128          // rows per block (8 waves x 16 rows)  [r7-verified]
#define MAXC     16           // candidate capacity (r14-verified collection path;
                              //   32->16 cuts LDS 55.3->47KB => 3 blocks/CU)
#define TPR      8            // tiles per round (16 codes each, 1/wave)
#define NRND     8            // rounds (single pass)
#define NBLK     (NROWS / RPB)   // 512 blocks
#define WS_NEED  (4096 + 131072 + 4096)   // bn + ebf + psum

typedef short  short8 __attribute__((ext_vector_type(8)));   // 8 bf16
typedef float  f32x4  __attribute__((ext_vector_type(4)));

// Async global->LDS, 16B/lane (r10-verified; m97/m104 semantics).
__device__ __forceinline__ void async_copy16(void* lds, const void* g) {
    __builtin_amdgcn_global_load_lds(
        (const __attribute__((address_space(1))) unsigned int*)g,
        (__attribute__((address_space(3))) unsigned int*)lds, 16, 0, 0);
}

// float -> bf16 bits, RNE. Filter-side only.
__device__ __forceinline__ unsigned short bf16rne(float x) {
    unsigned int u = __float_as_uint(x);
    return (unsigned short)((u + 0x7fffu + ((u >> 16) & 1u)) >> 16);
}

// numpy strided accumulator r_j for n=64 pairwise sum (r6/r7-verified).
__device__ __forceinline__ float np_acc8(const float* p, int j) {
#pragma clang fp contract(off)
    float r = 0.f;
#pragma unroll
    for (int i = 0; i < 8; ++i) {
        const float v = p[8 * i + j];
        r += v * v;
    }
    return r;
}

// Prep (r5 layout, verified): norms bit-exact + fragment-ordered ebf:
// tile g stored as [1024B b0 frags in lane order][1024B b1 frags].
// SEPARATE DISPATCH is load-bearing: the kernel boundary flushes/invalidates
// caches so all XCDs read fresh ebf/bn (r13 cooperative fusion produced
// stale-L2 garbage indices — do not re-fuse without cache-control asm).
__global__ void vq_prep(const float* __restrict__ emb,
                        float* __restrict__ bn,
                        unsigned short* __restrict__ ebf) {
#pragma clang fp contract(off)
    const int gtid = blockIdx.x * 256 + threadIdx.x;   // 8192 threads
    const int code = gtid >> 3;
    const int j    = gtid & 7;
    const float* ep = emb + (size_t)code * DD;
    float r = 0.f;
#pragma unroll
    for (int i = 0; i < 8; ++i) {
        const float v = ep[8 * i + j];
        r += v * v;
    }
    const float s1 = r  + __shfl_xor(r,  1, 64);
    const float s2 = s1 + __shfl_xor(s1, 2, 64);
    const float s3 = s2 + __shfl_xor(s2, 4, 64);
    if (j == 0) bn[code] = s3;

    const float* cp = emb + (size_t)gtid * 8;
    const float4 u0 = *reinterpret_cast<const float4*>(cp);
    const float4 u1 = *reinterpret_cast<const float4*>(cp + 4);
    short8 s;
    s[0] = (short)bf16rne(u0.x); s[1] = (short)bf16rne(u0.y);
    s[2] = (short)bf16rne(u0.z); s[3] = (short)bf16rne(u0.w);
    s[4] = (short)bf16rne(u1.x); s[5] = (short)bf16rne(u1.y);
    s[6] = (short)bf16rne(u1.z); s[7] = (short)bf16rne(u1.w);
    const int g    = code >> 4;
    const int c16s = code & 15;
    const int half = j >> 2;
    const int qq   = j & 3;
    const size_t doff = (size_t)g * 1024 + half * 512 + (qq * 16 + c16s) * 8;
    *reinterpret_cast<short8*>(ebf + doff) = s;
}

// Main — r11 VERBATIM (51.5-53.3us, absmax 0.0: 8 waves, RPB=128, TPR=8,
// NRND=8, double-buffered global_load_lds, per-round __syncthreads,
// rolling-threshold single pass, exact np rescore, coalesced epilogue,
// psum loss sink) with ONE variable changed: MAXC 32->16. LDS drops
// 55.3->~47KB => 3 blocks/CU (24 waves/CU, +50% TLP). Overflow rows take
// the verified full-K fallback (rare: typical candidate count 5-10).
__global__ __launch_bounds__(512, 4)
void vq_main(const float* __restrict__ z, const float* __restrict__ emb,
             const unsigned short* __restrict__ ebf,
             const float* __restrict__ bn, float* __restrict__ out,
             double* __restrict__ psum) {
    __shared__ char  dbuf[2][TPR * 2048] __attribute__((aligned(16)));  // 32 KB
    __shared__ float a_s[RPB];
    __shared__ float bn_s[KK];
    __shared__ int   cnt[RPB];
    __shared__ int   clist[RPB][MAXC];
    __shared__ int   bidx[RPB];
    __shared__ double lsum[8];

    const int tid  = threadIdx.x;
    const int lane = tid & 63;
    const int wv   = __builtin_amdgcn_readfirstlane(tid) >> 6;   // 0..7
    const int q    = lane >> 4;        // 0..3
    const int c16  = lane & 15;
    const int rowbase = blockIdx.x * RPB;

    // staging source: tile g at ebf + g*2048 bytes, lane reads its own 16B
    // at +lane*16 (b0 KB) and +1024+lane*16 (b1 KB) — contiguous, coalesced.
    const char* sbase = (const char*)ebf + (size_t)lane * 16;
    char* dst0 = &dbuf[0][wv * 2048 + lane * 16];
    char* dst1 = &dbuf[1][wv * 2048 + lane * 16];

    // ---- phase A: exact row norms, 8 lanes/row, all waves, 2 sweeps ----
    {
        const int j8 = tid & 7;
#pragma unroll
        for (int sw = 0; sw < 2; ++sw) {
            const int rowl = 64 * sw + (tid >> 3);   // 0..127
            const float r = np_acc8(z + (size_t)(rowbase + rowl) * DD, j8);
            const float s1 = r  + __shfl_xor(r,  1, 64);
            const float s2 = s1 + __shfl_xor(s1, 2, 64);
            const float s3 = s2 + __shfl_xor(s2, 4, 64);
            if (j8 == 0) a_s[rowl] = s3;
        }
    }
    if (tid < RPB) cnt[tid] = 0;
    {
        const int i = tid * 2;
        *reinterpret_cast<float2*>(&bn_s[i]) =
            *reinterpret_cast<const float2*>(bn + i);
    }

    // ---- A-fragments (verified layout): rows 16wv+c16, k=32kh+8q+j ----
    short8 afr[2];
#pragma unroll
    for (int kh = 0; kh < 2; ++kh) {
        const float* zp = z + (size_t)(rowbase + 16 * wv + c16) * DD
                          + 32 * kh + 8 * q;
        const float4 u0 = *reinterpret_cast<const float4*>(zp);
        const float4 u1 = *reinterpret_cast<const float4*>(zp + 4);
        short8 s;
        s[0] = (short)bf16rne(u0.x); s[1] = (short)bf16rne(u0.y);
        s[2] = (short)bf16rne(u0.z); s[3] = (short)bf16rne(u0.w);
        s[4] = (short)bf16rne(u1.x); s[5] = (short)bf16rne(u1.y);
        s[6] = (short)bf16rne(u1.z); s[7] = (short)bf16rne(u1.w);
        afr[kh] = s;
    }

    // wave stages tile (TPR*R + wv) of each round: 2 coalesced async copies
    auto stage = [&](int R, int buf) {
        const char* s0 = sbase + (size_t)(TPR * R + wv) * 2048;
        char* d = buf ? dst1 : dst0;
        async_copy16(d,        s0);
        async_copy16(d + 1024, s0 + 1024);
    };

    stage(0, 0);          // prologue (barrier also publishes phase-A LDS)
    __syncthreads();

    // W = 1.8e-4*||z|| + 1.2e-4 (verified window), per acc reg
    float wadd[4];
#pragma unroll
    for (int i = 0; i < 4; ++i) {
        const int rowl = 16 * wv + 4 * q + i;
        wadd[i] = 1.8e-4f * sqrtf(a_s[rowl]) + 1.2e-4f;
    }

    float mn[4];
#pragma unroll
    for (int i = 0; i < 4; ++i) mn[i] = FLT_MAX;

    // ============ single pass: 8 rounds x 8 tiles, rolling threshold ============
    for (int R = 0; R < NRND; ++R) {
        const int cur = R & 1;
        if (R < NRND - 1) stage(R + 1, cur ^ 1);
        float dv[TPR][4];
#pragma unroll
        for (int j = 0; j < TPR; ++j) {
            const char* tb = &dbuf[cur][j * 2048 + lane * 16];
            const short8 b0 = *reinterpret_cast<const short8*>(tb);
            const short8 b1 = *reinterpret_cast<const short8*>(tb + 1024);
            f32x4 acc = {0.f, 0.f, 0.f, 0.f};
            acc = __builtin_amdgcn_mfma_f32_16x16x32_bf16(afr[0], b0, acc, 0, 0, 0);
            acc = __builtin_amdgcn_mfma_f32_16x16x32_bf16(afr[1], b1, acc, 0, 0, 0);
            const float bnv = bn_s[16 * (TPR * R + j) + c16];
#pragma unroll
            for (int r = 0; r < 4; ++r)
                dv[j][r] = fmaf(-2.f, acc[r], bnv);
        }
        // rolling per-lane min, then cross-lane min over the 16 column-lanes
#pragma unroll
        for (int j = 0; j < TPR; ++j)
#pragma unroll
            for (int r = 0; r < 4; ++r)
                mn[r] = fminf(mn[r], dv[j][r]);
#pragma unroll
        for (int mask = 1; mask < 16; mask <<= 1)
#pragma unroll
            for (int r = 0; r < 4; ++r)
                mn[r] = fminf(mn[r], __shfl_xor(mn[r], mask, 64));
        float thr[4];
#pragma unroll
        for (int r = 0; r < 4; ++r) thr[r] = mn[r] + wadd[r];
        // collect (thr includes this round -> superset of final-min set)
#pragma unroll
        for (int j = 0; j < TPR; ++j) {
            const int col = 16 * (TPR * R + j) + c16;
#pragma unroll
            for (int r = 0; r < 4; ++r) {
                if (dv[j][r] <= thr[r]) {
                    const int rowl = 16 * wv + 4 * q + r;
                    const int slot = atomicAdd(&cnt[rowl], 1);
                    if (slot < MAXC) clist[rowl][slot] = col;
                }
            }
        }
        __syncthreads();   // publish next buffer (vmcnt drained), free cur
    }

    // ---- rescore (verified): exact np chain, lexic (s,k) min ----
    {
        const int rowl = 16 * wv + c16;
        const int row  = rowbase + rowl;
        const int nc   = cnt[rowl];     // rows are wave-private
        const bool full = nc > MAXC;    // overflow insurance
        const int lim  = full ? KK : nc;
        const float av = a_s[rowl];
        const float* zp = z + (size_t)row * DD;
        float sb = FLT_MAX;
        int   cb = 0x7fffffff;
        for (int jj = q; jj < lim; jj += 4) {
            const int c = full ? jj : clist[rowl][jj];
            const float* ep = emb + (size_t)c * DD;
            float dot = 0.f;
#pragma unroll
            for (int d = 0; d < DD; d += 4) {
                const float4 zv = *reinterpret_cast<const float4*>(zp + d);
                const float4 ev = *reinterpret_cast<const float4*>(ep + d);
                dot = fmaf(zv.x, ev.x, dot); dot = fmaf(zv.y, ev.y, dot);
                dot = fmaf(zv.z, ev.z, dot); dot = fmaf(zv.w, ev.w, dot);
            }
            const float tt = av + bn_s[c];
            const float sd = fmaf(-2.f, dot, tt);
            if (sd < sb || (sd == sb && c < cb)) { sb = sd; cb = c; }
        }
#pragma unroll
        for (int mask = 16; mask < 64; mask <<= 1) {
            const float so = __shfl_xor(sb, mask, 64);
            const int   co = __shfl_xor(cb, mask, 64);
            if (so < sb || (so == sb && co < cb)) { sb = so; cb = co; }
        }
        if (cb > 1023) cb = 0;   // safety: never OOB even if logic broke
        if (q == 0) bidx[rowl] = cb;
    }
    __syncthreads();

    // ---- epilogue: 4 threads/row (64B each), all waves, coalesced ----
    {
        const int rowl = tid >> 2;        // 0..127
        const int sub  = tid & 3;         // 0..3, owns floats sub*16..+15
        const int row  = rowbase + rowl;
        const int bid  = bidx[rowl];
        const float* ep = emb + (size_t)bid * DD + sub * 16;
        const float* zp = z + (size_t)row * DD + sub * 16;
        float* op = out + (size_t)row * DD + sub * 16;
        double sac = 0.0;
#pragma unroll
        for (int d = 0; d < 16; d += 4) {
            const float4 zv = *reinterpret_cast<const float4*>(zp + d);
            const float4 e4 = *reinterpret_cast<const float4*>(ep + d);
            const float df0 = e4.x - zv.x;
            const float df1 = e4.y - zv.y;
            const float df2 = e4.z - zv.z;
            const float df3 = e4.w - zv.w;
            float4 qv;
            qv.x = zv.x + df0; qv.y = zv.y + df1;
            qv.z = zv.z + df2; qv.w = zv.w + df3;
            *reinterpret_cast<float4*>(op + d) = qv;
            sac += (double)(df0 * df0); sac += (double)(df1 * df1);
            sac += (double)(df2 * df2); sac += (double)(df3 * df3);
        }
        if (sub == 0) out[IDX_OFF + row] = (float)bid;

        // combine 4 partials per row, then wave sum, then block partial.
        sac += __shfl_down(sac, 1, 64);
        sac += __shfl_down(sac, 2, 64);
        double v = (sub == 0) ? sac : 0.0;
#pragma unroll
        for (int off = 32; off > 0; off >>= 1) v += __shfl_down(v, off, 64);
        if (lane == 0) lsum[wv] = v;
    }
    __syncthreads();
    if (tid == 0) {
        double t = 0.0;
#pragma unroll
        for (int i = 0; i < 8; ++i) t += lsum[i];
        if (psum != nullptr)
            psum[blockIdx.x] = t;   // contention-free partial (vq_fin reduces)
        else
            atomicAdd(&out[LOSS_OFF], (float)((1.25 * t) / 262144.0));
    }
}

// Final reduce: one wave sums the 512 block partials and applies the loss once.
__global__ void vq_fin(const double* __restrict__ psum,
                       float* __restrict__ out) {
    const int lane = threadIdx.x;      // 64 threads
    double t = 0.0;
#pragma unroll
    for (int i = 0; i < 8; ++i) t += psum[lane * 8 + i];
#pragma unroll
    for (int off = 32; off > 0; off >>= 1) t += __shfl_down(t, off, 64);
    if (lane == 0)
        atomicAdd(&out[LOSS_OFF], (float)((1.25 * t) / 262144.0));
}

extern "C" void kernel_launch(void* const* d_in, const int* in_sizes, int n_in,
                              void* d_out, int out_size, void* d_ws, size_t ws_size,
                              hipStream_t stream) {
    const float* z   = (const float*)d_in[0];   // [16,4096,64] fp32
    const float* emb = (const float*)d_in[1];   // [1024,64] fp32
    float* out = (float*)d_out;                 // zq | loss | idx (flat fp32)

    float*          bnw  = (float*)d_ws;                            // 4 KB
    unsigned short* ebf  = (unsigned short*)((char*)d_ws + 4096);   // 128 KB
    // psum only if the workspace provably fits it (r9/r10 failure audit).
    double* psum = (ws_size >= (size_t)WS_NEED)
                   ? (double*)((char*)d_ws + 4096 + 131072) : nullptr;

    vq_prep<<<dim3(32), dim3(256), 0, stream>>>(emb, bnw, ebf);
    vq_main<<<dim3(NBLK), dim3(512), 0, stream>>>(z, emb, ebf, bnw, out, psum);
    if (psum != nullptr)
        vq_fin<<<dim3(1), dim3(64), 0, stream>>>(psum, out);
}

// Round 16
// 116.619 us; speedup vs baseline: 2.2648x; 1.9627x over previous
//
#include <hip/hip_runtime.h>
#include <math.h>
#include <float.h>

// Problem constants (B=16, T=4096, D=64, K=1024)
#define NROWS    65536
#define DD       64
#define KK       1024
#define LOSS_OFF 4194304
#define IDX_OFF  4194305
#define RPB      128          // rows per block (8 waves x 16 rows)  [r7-verified]
#define MAXC     32           // DO NOT REDUCE: counts run 17-32; MAXC=16 (r14/r15)
                              //   mass-overflowed into the full-K fallback (3-4x)
#define TPR      8            // tiles per round (16 codes each, 1/wave)
#define NRND     8            // rounds (single pass)
#define NBLK     (NROWS / RPB)   // 512 blocks
#define WS_NEED  (4096 + 131072 + 4096)   // bn + ebf + psum

typedef short  short8 __attribute__((ext_vector_type(8)));   // 8 bf16
typedef float  f32x4  __attribute__((ext_vector_type(4)));

// Async global->LDS, 16B/lane (r10-verified; m97/m104 semantics).
__device__ __forceinline__ void async_copy16(void* lds, const void* g) {
    __builtin_amdgcn_global_load_lds(
        (const __attribute__((address_space(1))) unsigned int*)g,
        (__attribute__((address_space(3))) unsigned int*)lds, 16, 0, 0);
}

// float -> bf16 bits, RNE. Filter-side only.
__device__ __forceinline__ unsigned short bf16rne(float x) {
    unsigned int u = __float_as_uint(x);
    return (unsigned short)((u + 0x7fffu + ((u >> 16) & 1u)) >> 16);
}

// numpy strided accumulator r_j for n=64 pairwise sum (r6/r7-verified).
__device__ __forceinline__ float np_acc8(const float* p, int j) {
#pragma clang fp contract(off)
    float r = 0.f;
#pragma unroll
    for (int i = 0; i < 8; ++i) {
        const float v = p[8 * i + j];
        r += v * v;
    }
    return r;
}

// Prep (r5 layout, verified): norms bit-exact + fragment-ordered ebf:
// tile g stored as [1024B b0 frags in lane order][1024B b1 frags].
// SEPARATE DISPATCH is load-bearing: the kernel boundary flushes/invalidates
// caches so all XCDs read fresh ebf/bn (r13 cooperative fusion produced
// stale-L2 garbage indices — do not re-fuse without cache-control asm).
__global__ void vq_prep(const float* __restrict__ emb,
                        float* __restrict__ bn,
                        unsigned short* __restrict__ ebf) {
#pragma clang fp contract(off)
    const int gtid = blockIdx.x * 256 + threadIdx.x;   // 8192 threads
    const int code = gtid >> 3;
    const int j    = gtid & 7;
    const float* ep = emb + (size_t)code * DD;
    float r = 0.f;
#pragma unroll
    for (int i = 0; i < 8; ++i) {
        const float v = ep[8 * i + j];
        r += v * v;
    }
    const float s1 = r  + __shfl_xor(r,  1, 64);
    const float s2 = s1 + __shfl_xor(s1, 2, 64);
    const float s3 = s2 + __shfl_xor(s2, 4, 64);
    if (j == 0) bn[code] = s3;

    const float* cp = emb + (size_t)gtid * 8;
    const float4 u0 = *reinterpret_cast<const float4*>(cp);
    const float4 u1 = *reinterpret_cast<const float4*>(cp + 4);
    short8 s;
    s[0] = (short)bf16rne(u0.x); s[1] = (short)bf16rne(u0.y);
    s[2] = (short)bf16rne(u0.z); s[3] = (short)bf16rne(u0.w);
    s[4] = (short)bf16rne(u1.x); s[5] = (short)bf16rne(u1.y);
    s[6] = (short)bf16rne(u1.z); s[7] = (short)bf16rne(u1.w);
    const int g    = code >> 4;
    const int c16s = code & 15;
    const int half = j >> 2;
    const int qq   = j & 3;
    const size_t doff = (size_t)g * 1024 + half * 512 + (qq * 16 + c16s) * 8;
    *reinterpret_cast<short8*>(ebf + doff) = s;
}

// Main — r11 VERBATIM (51.5-53.3us, absmax 0.0: 8 waves, RPB=128, TPR=8,
// NRND=8, double-buffered global_load_lds, per-round __syncthreads,
// rolling-threshold single pass, MAXC=32, exact np rescore, coalesced
// epilogue, psum loss sink) with ONE storage change: clist is unsigned
// short (cols < 1024). LDS 55.3 -> ~46.7KB => 3 blocks/CU (24 waves/CU,
// +50% TLP) with the verified MAXC=32 semantics fully intact.
__global__ __launch_bounds__(512, 4)
void vq_main(const float* __restrict__ z, const float* __restrict__ emb,
             const unsigned short* __restrict__ ebf,
             const float* __restrict__ bn, float* __restrict__ out,
             double* __restrict__ psum) {
    __shared__ char  dbuf[2][TPR * 2048] __attribute__((aligned(16)));  // 32 KB
    __shared__ float a_s[RPB];
    __shared__ float bn_s[KK];
    __shared__ int   cnt[RPB];
    __shared__ unsigned short clist[RPB][MAXC];   // 8 KB (was 16)
    __shared__ int   bidx[RPB];
    __shared__ double lsum[8];

    const int tid  = threadIdx.x;
    const int lane = tid & 63;
    const int wv   = __builtin_amdgcn_readfirstlane(tid) >> 6;   // 0..7
    const int q    = lane >> 4;        // 0..3
    const int c16  = lane & 15;
    const int rowbase = blockIdx.x * RPB;

    // staging source: tile g at ebf + g*2048 bytes, lane reads its own 16B
    // at +lane*16 (b0 KB) and +1024+lane*16 (b1 KB) — contiguous, coalesced.
    const char* sbase = (const char*)ebf + (size_t)lane * 16;
    char* dst0 = &dbuf[0][wv * 2048 + lane * 16];
    char* dst1 = &dbuf[1][wv * 2048 + lane * 16];

    // ---- phase A: exact row norms, 8 lanes/row, all waves, 2 sweeps ----
    {
        const int j8 = tid & 7;
#pragma unroll
        for (int sw = 0; sw < 2; ++sw) {
            const int rowl = 64 * sw + (tid >> 3);   // 0..127
            const float r = np_acc8(z + (size_t)(rowbase + rowl) * DD, j8);
            const float s1 = r  + __shfl_xor(r,  1, 64);
            const float s2 = s1 + __shfl_xor(s1, 2, 64);
            const float s3 = s2 + __shfl_xor(s2, 4, 64);
            if (j8 == 0) a_s[rowl] = s3;
        }
    }
    if (tid < RPB) cnt[tid] = 0;
    {
        const int i = tid * 2;
        *reinterpret_cast<float2*>(&bn_s[i]) =
            *reinterpret_cast<const float2*>(bn + i);
    }

    // ---- A-fragments (verified layout): rows 16wv+c16, k=32kh+8q+j ----
    short8 afr[2];
#pragma unroll
    for (int kh = 0; kh < 2; ++kh) {
        const float* zp = z + (size_t)(rowbase + 16 * wv + c16) * DD
                          + 32 * kh + 8 * q;
        const float4 u0 = *reinterpret_cast<const float4*>(zp);
        const float4 u1 = *reinterpret_cast<const float4*>(zp + 4);
        short8 s;
        s[0] = (short)bf16rne(u0.x); s[1] = (short)bf16rne(u0.y);
        s[2] = (short)bf16rne(u0.z); s[3] = (short)bf16rne(u0.w);
        s[4] = (short)bf16rne(u1.x); s[5] = (short)bf16rne(u1.y);
        s[6] = (short)bf16rne(u1.z); s[7] = (short)bf16rne(u1.w);
        afr[kh] = s;
    }

    // wave stages tile (TPR*R + wv) of each round: 2 coalesced async copies
    auto stage = [&](int R, int buf) {
        const char* s0 = sbase + (size_t)(TPR * R + wv) * 2048;
        char* d = buf ? dst1 : dst0;
        async_copy16(d,        s0);
        async_copy16(d + 1024, s0 + 1024);
    };

    stage(0, 0);          // prologue (barrier also publishes phase-A LDS)
    __syncthreads();

    // W = 1.8e-4*||z|| + 1.2e-4 (verified window), per acc reg
    float wadd[4];
#pragma unroll
    for (int i = 0; i < 4; ++i) {
        const int rowl = 16 * wv + 4 * q + i;
        wadd[i] = 1.8e-4f * sqrtf(a_s[rowl]) + 1.2e-4f;
    }

    float mn[4];
#pragma unroll
    for (int i = 0; i < 4; ++i) mn[i] = FLT_MAX;

    // ============ single pass: 8 rounds x 8 tiles, rolling threshold ============
    for (int R = 0; R < NRND; ++R) {
        const int cur = R & 1;
        if (R < NRND - 1) stage(R + 1, cur ^ 1);
        float dv[TPR][4];
#pragma unroll
        for (int j = 0; j < TPR; ++j) {
            const char* tb = &dbuf[cur][j * 2048 + lane * 16];
            const short8 b0 = *reinterpret_cast<const short8*>(tb);
            const short8 b1 = *reinterpret_cast<const short8*>(tb + 1024);
            f32x4 acc = {0.f, 0.f, 0.f, 0.f};
            acc = __builtin_amdgcn_mfma_f32_16x16x32_bf16(afr[0], b0, acc, 0, 0, 0);
            acc = __builtin_amdgcn_mfma_f32_16x16x32_bf16(afr[1], b1, acc, 0, 0, 0);
            const float bnv = bn_s[16 * (TPR * R + j) + c16];
#pragma unroll
            for (int r = 0; r < 4; ++r)
                dv[j][r] = fmaf(-2.f, acc[r], bnv);
        }
        // rolling per-lane min, then cross-lane min over the 16 column-lanes
#pragma unroll
        for (int j = 0; j < TPR; ++j)
#pragma unroll
            for (int r = 0; r < 4; ++r)
                mn[r] = fminf(mn[r], dv[j][r]);
#pragma unroll
        for (int mask = 1; mask < 16; mask <<= 1)
#pragma unroll
            for (int r = 0; r < 4; ++r)
                mn[r] = fminf(mn[r], __shfl_xor(mn[r], mask, 64));
        float thr[4];
#pragma unroll
        for (int r = 0; r < 4; ++r) thr[r] = mn[r] + wadd[r];
        // collect (thr includes this round -> superset of final-min set)
#pragma unroll
        for (int j = 0; j < TPR; ++j) {
            const int col = 16 * (TPR * R + j) + c16;
#pragma unroll
            for (int r = 0; r < 4; ++r) {
                if (dv[j][r] <= thr[r]) {
                    const int rowl = 16 * wv + 4 * q + r;
                    const int slot = atomicAdd(&cnt[rowl], 1);
                    if (slot < MAXC) clist[rowl][slot] = (unsigned short)col;
                }
            }
        }
        __syncthreads();   // publish next buffer (vmcnt drained), free cur
    }

    // ---- rescore (verified): exact np chain, lexic (s,k) min ----
    {
        const int rowl = 16 * wv + c16;
        const int row  = rowbase + rowl;
        const int nc   = cnt[rowl];     // rows are wave-private
        const bool full = nc > MAXC;    // overflow insurance
        const int lim  = full ? KK : nc;
        const float av = a_s[rowl];
        const float* zp = z + (size_t)row * DD;
        float sb = FLT_MAX;
        int   cb = 0x7fffffff;
        for (int jj = q; jj < lim; jj += 4) {
            const int c = full ? jj : (int)clist[rowl][jj];
            const float* ep = emb + (size_t)c * DD;
            float dot = 0.f;
#pragma unroll
            for (int d = 0; d < DD; d += 4) {
                const float4 zv = *reinterpret_cast<const float4*>(zp + d);
                const float4 ev = *reinterpret_cast<const float4*>(ep + d);
                dot = fmaf(zv.x, ev.x, dot); dot = fmaf(zv.y, ev.y, dot);
                dot = fmaf(zv.z, ev.z, dot); dot = fmaf(zv.w, ev.w, dot);
            }
            const float tt = av + bn_s[c];
            const float sd = fmaf(-2.f, dot, tt);
            if (sd < sb || (sd == sb && c < cb)) { sb = sd; cb = c; }
        }
#pragma unroll
        for (int mask = 16; mask < 64; mask <<= 1) {
            const float so = __shfl_xor(sb, mask, 64);
            const int   co = __shfl_xor(cb, mask, 64);
            if (so < sb || (so == sb && co < cb)) { sb = so; cb = co; }
        }
        if (cb > 1023) cb = 0;   // safety: never OOB even if logic broke
        if (q == 0) bidx[rowl] = cb;
    }
    __syncthreads();

    // ---- epilogue: 4 threads/row (64B each), all waves, coalesced ----
    {
        const int rowl = tid >> 2;        // 0..127
        const int sub  = tid & 3;         // 0..3, owns floats sub*16..+15
        const int row  = rowbase + rowl;
        const int bid  = bidx[rowl];
        const float* ep = emb + (size_t)bid * DD + sub * 16;
        const float* zp = z + (size_t)row * DD + sub * 16;
        float* op = out + (size_t)row * DD + sub * 16;
        double sac = 0.0;
#pragma unroll
        for (int d = 0; d < 16; d += 4) {
            const float4 zv = *reinterpret_cast<const float4*>(zp + d);
            const float4 e4 = *reinterpret_cast<const float4*>(ep + d);
            const float df0 = e4.x - zv.x;
            const float df1 = e4.y - zv.y;
            const float df2 = e4.z - zv.z;
            const float df3 = e4.w - zv.w;
            float4 qv;
            qv.x = zv.x + df0; qv.y = zv.y + df1;
            qv.z = zv.z + df2; qv.w = zv.w + df3;
            *reinterpret_cast<float4*>(op + d) = qv;
            sac += (double)(df0 * df0); sac += (double)(df1 * df1);
            sac += (double)(df2 * df2); sac += (double)(df3 * df3);
        }
        if (sub == 0) out[IDX_OFF + row] = (float)bid;

        // combine 4 partials per row, then wave sum, then block partial.
        sac += __shfl_down(sac, 1, 64);
        sac += __shfl_down(sac, 2, 64);
        double v = (sub == 0) ? sac : 0.0;
#pragma unroll
        for (int off = 32; off > 0; off >>= 1) v += __shfl_down(v, off, 64);
        if (lane == 0) lsum[wv] = v;
    }
    __syncthreads();
    if (tid == 0) {
        double t = 0.0;
#pragma unroll
        for (int i = 0; i < 8; ++i) t += lsum[i];
        if (psum != nullptr)
            psum[blockIdx.x] = t;   // contention-free partial (vq_fin reduces)
        else
            atomicAdd(&out[LOSS_OFF], (float)((1.25 * t) / 262144.0));
    }
}

// Final reduce: one wave sums the 512 block partials and applies the loss once.
__global__ void vq_fin(const double* __restrict__ psum,
                       float* __restrict__ out) {
    const int lane = threadIdx.x;      // 64 threads
    double t = 0.0;
#pragma unroll
    for (int i = 0; i < 8; ++i) t += psum[lane * 8 + i];
#pragma unroll
    for (int off = 32; off > 0; off >>= 1) t += __shfl_down(t, off, 64);
    if (lane == 0)
        atomicAdd(&out[LOSS_OFF], (float)((1.25 * t) / 262144.0));
}

extern "C" void kernel_launch(void* const* d_in, const int* in_sizes, int n_in,
                              void* d_out, int out_size, void* d_ws, size_t ws_size,
                              hipStream_t stream) {
    const float* z   = (const float*)d_in[0];   // [16,4096,64] fp32
    const float* emb = (const float*)d_in[1];   // [1024,64] fp32
    float* out = (float*)d_out;                 // zq | loss | idx (flat fp32)

    float*          bnw  = (float*)d_ws;                            // 4 KB
    unsigned short* ebf  = (unsigned short*)((char*)d_ws + 4096);   // 128 KB
    // psum only if the workspace provably fits it (r9/r10 failure audit).
    double* psum = (ws_size >= (size_t)WS_NEED)
                   ? (double*)((char*)d_ws + 4096 + 131072) : nullptr;

    vq_prep<<<dim3(32), dim3(256), 0, stream>>>(emb, bnw, ebf);
    vq_main<<<dim3(NBLK), dim3(512), 0, stream>>>(z, emb, ebf, bnw, out, psum);
    if (psum != nullptr)
        vq_fin<<<dim3(1), dim3(64), 0, stream>>>(psum, out);
}

// Round 17
// 115.815 us; speedup vs baseline: 2.2805x; 1.0069x over previous
//
#include <hip/hip_runtime.h>
#include <math.h>
#include <float.h>

// Problem constants (B=16, T=4096, D=64, K=1024)
#define NROWS    65536
#define DD       64
#define KK       1024
#define LOSS_OFF 4194304
#define IDX_OFF  4194305
#define RPB      128          // rows per block (8 waves x 16 rows)  [r7-verified]
#define MAXC     32           // DO NOT REDUCE (r14/r15: MAXC=16 mass-overflows
                              //   into the full-K fallback, 3-4x slowdown).
                              //   Keep int (r16: ushort clist cost +6us).
#define TPR      8            // tiles per round (16 codes each, 1/wave)
#define NRND     8            // rounds (single pass)
#define NBLK     (NROWS / RPB)   // 512 blocks = exactly 2 blocks/CU
#define WS_NEED  (4096 + 131072 + 4096)   // bn + ebf + psum

typedef short  short8 __attribute__((ext_vector_type(8)));   // 8 bf16
typedef float  f32x4  __attribute__((ext_vector_type(4)));

// Async global->LDS, 16B/lane (r10-verified; m97/m104 semantics).
__device__ __forceinline__ void async_copy16(void* lds, const void* g) {
    __builtin_amdgcn_global_load_lds(
        (const __attribute__((address_space(1))) unsigned int*)g,
        (__attribute__((address_space(3))) unsigned int*)lds, 16, 0, 0);
}

// float -> bf16 bits, RNE. Filter-side only.
__device__ __forceinline__ unsigned short bf16rne(float x) {
    unsigned int u = __float_as_uint(x);
    return (unsigned short)((u + 0x7fffu + ((u >> 16) & 1u)) >> 16);
}

// numpy strided accumulator r_j for n=64 pairwise sum (r6/r7-verified).
__device__ __forceinline__ float np_acc8(const float* p, int j) {
#pragma clang fp contract(off)
    float r = 0.f;
#pragma unroll
    for (int i = 0; i < 8; ++i) {
        const float v = p[8 * i + j];
        r += v * v;
    }
    return r;
}

// Prep (r5 layout, verified): norms bit-exact + fragment-ordered ebf:
// tile g stored as [1024B b0 frags in lane order][1024B b1 frags].
// SEPARATE DISPATCH is load-bearing: the kernel boundary flushes/invalidates
// caches so all XCDs read fresh ebf/bn (r13 cooperative fusion produced
// stale-L2 garbage indices — do not re-fuse without cache-control asm).
__global__ void vq_prep(const float* __restrict__ emb,
                        float* __restrict__ bn,
                        unsigned short* __restrict__ ebf) {
#pragma clang fp contract(off)
    const int gtid = blockIdx.x * 256 + threadIdx.x;   // 8192 threads
    const int code = gtid >> 3;
    const int j    = gtid & 7;
    const float* ep = emb + (size_t)code * DD;
    float r = 0.f;
#pragma unroll
    for (int i = 0; i < 8; ++i) {
        const float v = ep[8 * i + j];
        r += v * v;
    }
    const float s1 = r  + __shfl_xor(r,  1, 64);
    const float s2 = s1 + __shfl_xor(s1, 2, 64);
    const float s3 = s2 + __shfl_xor(s2, 4, 64);
    if (j == 0) bn[code] = s3;

    const float* cp = emb + (size_t)gtid * 8;
    const float4 u0 = *reinterpret_cast<const float4*>(cp);
    const float4 u1 = *reinterpret_cast<const float4*>(cp + 4);
    short8 s;
    s[0] = (short)bf16rne(u0.x); s[1] = (short)bf16rne(u0.y);
    s[2] = (short)bf16rne(u0.z); s[3] = (short)bf16rne(u0.w);
    s[4] = (short)bf16rne(u1.x); s[5] = (short)bf16rne(u1.y);
    s[6] = (short)bf16rne(u1.z); s[7] = (short)bf16rne(u1.w);
    const int g    = code >> 4;
    const int c16s = code & 15;
    const int half = j >> 2;
    const int qq   = j & 3;
    const size_t doff = (size_t)g * 1024 + half * 512 + (qq * 16 + c16s) * 8;
    *reinterpret_cast<short8*>(ebf + doff) = s;
}

// Main — r11 VERBATIM (best verified: 51.5-53.3us, absmax 0.0) with ONE
// change: stage(0) is issued at the very top, so the first tile's DMA
// completes under phase-A's cold-z HBM latency instead of serializing
// after it. The pre-loop __syncthreads still drains vmcnt -> semantics
// identical. Everything else (8 waves, RPB=128, TPR=8, NRND=8, dbuf[2],
// per-round __syncthreads, rolling threshold, MAXC=32 int clist, exact
// np rescore, coalesced epilogue, psum loss sink) is byte-identical.
__global__ __launch_bounds__(512, 4)
void vq_main(const float* __restrict__ z, const float* __restrict__ emb,
             const unsigned short* __restrict__ ebf,
             const float* __restrict__ bn, float* __restrict__ out,
             double* __restrict__ psum) {
    __shared__ char  dbuf[2][TPR * 2048] __attribute__((aligned(16)));  // 32 KB
    __shared__ float a_s[RPB];
    __shared__ float bn_s[KK];
    __shared__ int   cnt[RPB];
    __shared__ int   clist[RPB][MAXC];
    __shared__ int   bidx[RPB];
    __shared__ double lsum[8];

    const int tid  = threadIdx.x;
    const int lane = tid & 63;
    const int wv   = __builtin_amdgcn_readfirstlane(tid) >> 6;   // 0..7
    const int q    = lane >> 4;        // 0..3
    const int c16  = lane & 15;
    const int rowbase = blockIdx.x * RPB;

    // staging source: tile g at ebf + g*2048 bytes, lane reads its own 16B
    // at +lane*16 (b0 KB) and +1024+lane*16 (b1 KB) — contiguous, coalesced.
    const char* sbase = (const char*)ebf + (size_t)lane * 16;
    char* dst0 = &dbuf[0][wv * 2048 + lane * 16];
    char* dst1 = &dbuf[1][wv * 2048 + lane * 16];

    // wave stages tile (TPR*R + wv) of each round: 2 coalesced async copies
    auto stage = [&](int R, int buf) {
        const char* s0 = sbase + (size_t)(TPR * R + wv) * 2048;
        char* d = buf ? dst1 : dst0;
        async_copy16(d,        s0);
        async_copy16(d + 1024, s0 + 1024);
    };

    stage(0, 0);   // issue FIRST: DMA completes under phase-A's HBM latency

    // ---- phase A: exact row norms, 8 lanes/row, all waves, 2 sweeps ----
    {
        const int j8 = tid & 7;
#pragma unroll
        for (int sw = 0; sw < 2; ++sw) {
            const int rowl = 64 * sw + (tid >> 3);   // 0..127
            const float r = np_acc8(z + (size_t)(rowbase + rowl) * DD, j8);
            const float s1 = r  + __shfl_xor(r,  1, 64);
            const float s2 = s1 + __shfl_xor(s1, 2, 64);
            const float s3 = s2 + __shfl_xor(s2, 4, 64);
            if (j8 == 0) a_s[rowl] = s3;
        }
    }
    if (tid < RPB) cnt[tid] = 0;
    {
        const int i = tid * 2;
        *reinterpret_cast<float2*>(&bn_s[i]) =
            *reinterpret_cast<const float2*>(bn + i);
    }

    // ---- A-fragments (verified layout): rows 16wv+c16, k=32kh+8q+j ----
    short8 afr[2];
#pragma unroll
    for (int kh = 0; kh < 2; ++kh) {
        const float* zp = z + (size_t)(rowbase + 16 * wv + c16) * DD
                          + 32 * kh + 8 * q;
        const float4 u0 = *reinterpret_cast<const float4*>(zp);
        const float4 u1 = *reinterpret_cast<const float4*>(zp + 4);
        short8 s;
        s[0] = (short)bf16rne(u0.x); s[1] = (short)bf16rne(u0.y);
        s[2] = (short)bf16rne(u0.z); s[3] = (short)bf16rne(u0.w);
        s[4] = (short)bf16rne(u1.x); s[5] = (short)bf16rne(u1.y);
        s[6] = (short)bf16rne(u1.z); s[7] = (short)bf16rne(u1.w);
        afr[kh] = s;
    }

    __syncthreads();   // publishes phase-A LDS; drains stage(0) (vmcnt 0)

    // W = 1.8e-4*||z|| + 1.2e-4 (verified window), per acc reg
    float wadd[4];
#pragma unroll
    for (int i = 0; i < 4; ++i) {
        const int rowl = 16 * wv + 4 * q + i;
        wadd[i] = 1.8e-4f * sqrtf(a_s[rowl]) + 1.2e-4f;
    }

    float mn[4];
#pragma unroll
    for (int i = 0; i < 4; ++i) mn[i] = FLT_MAX;

    // ============ single pass: 8 rounds x 8 tiles, rolling threshold ============
    for (int R = 0; R < NRND; ++R) {
        const int cur = R & 1;
        if (R < NRND - 1) stage(R + 1, cur ^ 1);
        float dv[TPR][4];
#pragma unroll
        for (int j = 0; j < TPR; ++j) {
            const char* tb = &dbuf[cur][j * 2048 + lane * 16];
            const short8 b0 = *reinterpret_cast<const short8*>(tb);
            const short8 b1 = *reinterpret_cast<const short8*>(tb + 1024);
            f32x4 acc = {0.f, 0.f, 0.f, 0.f};
            acc = __builtin_amdgcn_mfma_f32_16x16x32_bf16(afr[0], b0, acc, 0, 0, 0);
            acc = __builtin_amdgcn_mfma_f32_16x16x32_bf16(afr[1], b1, acc, 0, 0, 0);
            const float bnv = bn_s[16 * (TPR * R + j) + c16];
#pragma unroll
            for (int r = 0; r < 4; ++r)
                dv[j][r] = fmaf(-2.f, acc[r], bnv);
        }
        // rolling per-lane min, then cross-lane min over the 16 column-lanes
#pragma unroll
        for (int j = 0; j < TPR; ++j)
#pragma unroll
            for (int r = 0; r < 4; ++r)
                mn[r] = fminf(mn[r], dv[j][r]);
#pragma unroll
        for (int mask = 1; mask < 16; mask <<= 1)
#pragma unroll
            for (int r = 0; r < 4; ++r)
                mn[r] = fminf(mn[r], __shfl_xor(mn[r], mask, 64));
        float thr[4];
#pragma unroll
        for (int r = 0; r < 4; ++r) thr[r] = mn[r] + wadd[r];
        // collect (thr includes this round -> superset of final-min set)
#pragma unroll
        for (int j = 0; j < TPR; ++j) {
            const int col = 16 * (TPR * R + j) + c16;
#pragma unroll
            for (int r = 0; r < 4; ++r) {
                if (dv[j][r] <= thr[r]) {
                    const int rowl = 16 * wv + 4 * q + r;
                    const int slot = atomicAdd(&cnt[rowl], 1);
                    if (slot < MAXC) clist[rowl][slot] = col;
                }
            }
        }
        __syncthreads();   // publish next buffer (vmcnt drained), free cur
    }

    // ---- rescore (verified): exact np chain, lexic (s,k) min ----
    {
        const int rowl = 16 * wv + c16;
        const int row  = rowbase + rowl;
        const int nc   = cnt[rowl];     // rows are wave-private
        const bool full = nc > MAXC;    // overflow insurance
        const int lim  = full ? KK : nc;
        const float av = a_s[rowl];
        const float* zp = z + (size_t)row * DD;
        float sb = FLT_MAX;
        int   cb = 0x7fffffff;
        for (int jj = q; jj < lim; jj += 4) {
            const int c = full ? jj : clist[rowl][jj];
            const float* ep = emb + (size_t)c * DD;
            float dot = 0.f;
#pragma unroll
            for (int d = 0; d < DD; d += 4) {
                const float4 zv = *reinterpret_cast<const float4*>(zp + d);
                const float4 ev = *reinterpret_cast<const float4*>(ep + d);
                dot = fmaf(zv.x, ev.x, dot); dot = fmaf(zv.y, ev.y, dot);
                dot = fmaf(zv.z, ev.z, dot); dot = fmaf(zv.w, ev.w, dot);
            }
            const float tt = av + bn_s[c];
            const float sd = fmaf(-2.f, dot, tt);
            if (sd < sb || (sd == sb && c < cb)) { sb = sd; cb = c; }
        }
#pragma unroll
        for (int mask = 16; mask < 64; mask <<= 1) {
            const float so = __shfl_xor(sb, mask, 64);
            const int   co = __shfl_xor(cb, mask, 64);
            if (so < sb || (so == sb && co < cb)) { sb = so; cb = co; }
        }
        if (cb > 1023) cb = 0;   // safety: never OOB even if logic broke
        if (q == 0) bidx[rowl] = cb;
    }
    __syncthreads();

    // ---- epilogue: 4 threads/row (64B each), all waves, coalesced ----
    {
        const int rowl = tid >> 2;        // 0..127
        const int sub  = tid & 3;         // 0..3, owns floats sub*16..+15
        const int row  = rowbase + rowl;
        const int bid  = bidx[rowl];
        const float* ep = emb + (size_t)bid * DD + sub * 16;
        const float* zp = z + (size_t)row * DD + sub * 16;
        float* op = out + (size_t)row * DD + sub * 16;
        double sac = 0.0;
#pragma unroll
        for (int d = 0; d < 16; d += 4) {
            const float4 zv = *reinterpret_cast<const float4*>(zp + d);
            const float4 e4 = *reinterpret_cast<const float4*>(ep + d);
            const float df0 = e4.x - zv.x;
            const float df1 = e4.y - zv.y;
            const float df2 = e4.z - zv.z;
            const float df3 = e4.w - zv.w;
            float4 qv;
            qv.x = zv.x + df0; qv.y = zv.y + df1;
            qv.z = zv.z + df2; qv.w = zv.w + df3;
            *reinterpret_cast<float4*>(op + d) = qv;
            sac += (double)(df0 * df0); sac += (double)(df1 * df1);
            sac += (double)(df2 * df2); sac += (double)(df3 * df3);
        }
        if (sub == 0) out[IDX_OFF + row] = (float)bid;

        // combine 4 partials per row, then wave sum, then block partial.
        sac += __shfl_down(sac, 1, 64);
        sac += __shfl_down(sac, 2, 64);
        double v = (sub == 0) ? sac : 0.0;
#pragma unroll
        for (int off = 32; off > 0; off >>= 1) v += __shfl_down(v, off, 64);
        if (lane == 0) lsum[wv] = v;
    }
    __syncthreads();
    if (tid == 0) {
        double t = 0.0;
#pragma unroll
        for (int i = 0; i < 8; ++i) t += lsum[i];
        if (psum != nullptr)
            psum[blockIdx.x] = t;   // contention-free partial (vq_fin reduces)
        else
            atomicAdd(&out[LOSS_OFF], (float)((1.25 * t) / 262144.0));
    }
}

// Final reduce: one wave sums the 512 block partials and applies the loss once.
__global__ void vq_fin(const double* __restrict__ psum,
                       float* __restrict__ out) {
    const int lane = threadIdx.x;      // 64 threads
    double t = 0.0;
#pragma unroll
    for (int i = 0; i < 8; ++i) t += psum[lane * 8 + i];
#pragma unroll
    for (int off = 32; off > 0; off >>= 1) t += __shfl_down(t, off, 64);
    if (lane == 0)
        atomicAdd(&out[LOSS_OFF], (float)((1.25 * t) / 262144.0));
}

extern "C" void kernel_launch(void* const* d_in, const int* in_sizes, int n_in,
                              void* d_out, int out_size, void* d_ws, size_t ws_size,
                              hipStream_t stream) {
    const float* z   = (const float*)d_in[0];   // [16,4096,64] fp32
    const float* emb = (const float*)d_in[1];   // [1024,64] fp32
    float* out = (float*)d_out;                 // zq | loss | idx (flat fp32)

    float*          bnw  = (float*)d_ws;                            // 4 KB
    unsigned short* ebf  = (unsigned short*)((char*)d_ws + 4096);   // 128 KB
    // psum only if the workspace provably fits it (r9/r10 failure audit).
    double* psum = (ws_size >= (size_t)WS_NEED)
                   ? (double*)((char*)d_ws + 4096 + 131072) : nullptr;

    vq_prep<<<dim3(32), dim3(256), 0, stream>>>(emb, bnw, ebf);
    vq_main<<<dim3(NBLK), dim3(512), 0, stream>>>(z, emb, ebf, bnw, out, psum);
    if (psum != nullptr)
        vq_fin<<<dim3(1), dim3(64), 0, stream>>>(psum, out);
}